// Round 5
// baseline (234.513 us; speedup 1.0000x reference)
//
#include <hip/hip_runtime.h>
#include <stdint.h>

typedef unsigned long long u64;
typedef unsigned int u32;

// Block = (slice, 32-column stripe): packs+dilates its FULL slice redundantly
// (8 sibling blocks per slice, all on the same XCD -> mask reads hit L2),
// reduces only its stripe. 1024 blocks -> 4 blocks/CU, 16 waves/CU for
// latency hiding (R4 at 256 blocks was 1 wave/SIMD, fully latency-exposed).
// d0 identity: sum_{k=0..20} dilate^k(edge) = max(0,21-d0); weight = 22-entry LUT.
__global__ __launch_bounds__(256, 4) void bbsd_fused(const float* __restrict__ outputs,
                                                     const int* __restrict__ masks,
                                                     float* __restrict__ acc,   // 6 floats, zeroed
                                                     u32* __restrict__ cnt,     // zeroed
                                                     float* __restrict__ out) {
    __shared__ u64 rows[256][5];   // mask bits per row (+pad col)
    __shared__ u64 tmp[256][5];    // dilation exchange
    __shared__ float wtab[22];
    __shared__ float red[4][3];

    const int t = threadIdx.x;              // row this thread owns
    const int lane = t & 63, wv = t >> 6;
    const int slice = blockIdx.x & 127;     // siblings b,b+128,..,b+896 ≡ b (mod 8): same XCD
    const int stripe = blockIdx.x >> 7;     // 0..7 -> columns [stripe*32, stripe*32+32)
    const int b = slice >> 6;               // batch

    if (t < 22) wtab[t] = 2.0f / (1.0f + __expf(10.0f * (float)(t + 1) * (1.0f / 22.0f)));

    // ---- pack row t: 64 independent int4 loads -> 4 u64 words ----
    u64 m[4] = {0ull, 0ull, 0ull, 0ull};
    {
        const int4* mp = (const int4*)(masks + (size_t)slice * 65536 + (size_t)t * 256);
        #pragma unroll
        for (int g = 0; g < 64; ++g) {
            int4 v = mp[g];
            u64 nib = (u64)(v.x != 0) | ((u64)(v.y != 0) << 1)
                    | ((u64)(v.z != 0) << 2) | ((u64)(v.w != 0) << 3);
            m[g >> 4] |= nib << ((g & 15) * 4);
        }
        #pragma unroll
        for (int j = 0; j < 4; ++j) rows[t][j] = m[j];
    }
    __syncthreads();

    // ---- edge = m & ~(up & dn & lf & rt), zero-padded ----
    u64 c[4];
    {
        u64 up[4], dn[4];
        #pragma unroll
        for (int j = 0; j < 4; ++j) {
            up[j] = (t > 0)   ? rows[t - 1][j] : 0ull;
            dn[j] = (t < 255) ? rows[t + 1][j] : 0ull;
        }
        #pragma unroll
        for (int j = 0; j < 4; ++j) {
            u64 lf = (m[j] << 1) | (j > 0 ? (m[j - 1] >> 63) : 0ull);
            u64 rt = (m[j] >> 1) | (j < 3 ? (m[j + 1] << 63) : 0ull);
            c[j] = m[j] & ~(up[j] & dn[j] & lf & rt);
        }
    }

    // ---- cascaded dilation, d0 recorded as 5 register bit-planes ----
    u64 p[5][4];
    #pragma unroll
    for (int pl = 0; pl < 5; ++pl)
        #pragma unroll
        for (int j = 0; j < 4; ++j) p[pl][j] = 0ull;

    for (int k = 1; k <= 20; ++k) {
        u64 hh[4];
        #pragma unroll
        for (int j = 0; j < 4; ++j) {
            u64 lf = (c[j] << 1) | (j > 0 ? (c[j - 1] >> 63) : 0ull);
            u64 rt = (c[j] >> 1) | (j < 3 ? (c[j + 1] << 63) : 0ull);
            hh[j] = c[j] | lf | rt;
            tmp[t][j] = hh[j];
        }
        __syncthreads();
        #pragma unroll
        for (int j = 0; j < 4; ++j) {
            u64 u_ = (t > 0)   ? tmp[t - 1][j] : 0ull;
            u64 d_ = (t < 255) ? tmp[t + 1][j] : 0ull;
            u64 n = hh[j] | u_ | d_;
            u64 nw = n & ~c[j];
            c[j] = n;
            #pragma unroll
            for (int pl = 0; pl < 5; ++pl) {
                u64 sel = (u64)0 - (u64)((k >> pl) & 1);   // branchless, k wave-uniform
                p[pl][j] |= nw & sel;
            }
        }
        int done = ((c[0] & c[1] & c[2] & c[3]) == 0xFFFFFFFFFFFFFFFFull) ? 1 : 0;
        if (__syncthreads_and(done)) break;   // also protects tmp reuse
    }

    // never covered within 20 rounds => d0 = 21 (0b10101)
    #pragma unroll
    for (int j = 0; j < 4; ++j) {
        u64 u_ = ~c[j];
        p[0][j] |= u_; p[2][j] |= u_; p[4][j] |= u_;
    }

    // ---- reduce: thread t = row t, columns [stripe*32, stripe*32+32) ----
    float s0 = 0.0f, s1 = 0.0f, s2 = 0.0f;
    {
        const int w = stripe >> 1;
        const int sh0 = (stripe & 1) * 32;
        u32 P0 = (u32)(p[0][w] >> sh0), P1 = (u32)(p[1][w] >> sh0);
        u32 P2 = (u32)(p[2][w] >> sh0), P3 = (u32)(p[3][w] >> sh0);
        u32 P4 = (u32)(p[4][w] >> sh0), M  = (u32)(m[w] >> sh0);
        const float4* op4 = (const float4*)(outputs + (size_t)slice * 65536
                                            + (size_t)t * 256 + stripe * 32);
        #pragma unroll
        for (int i = 0; i < 8; ++i) {
            float4 o4 = op4[i];
            float ov[4] = {o4.x, o4.y, o4.z, o4.w};
            #pragma unroll
            for (int q = 0; q < 4; ++q) {
                int bitix = i * 4 + q;
                int d0 = (int)((P0 >> bitix) & 1u)
                       | ((int)((P1 >> bitix) & 1u) << 1)
                       | ((int)((P2 >> bitix) & 1u) << 2)
                       | ((int)((P3 >> bitix) & 1u) << 3)
                       | ((int)((P4 >> bitix) & 1u) << 4);
                float wgt = wtab[d0];                // d0 in {0,1,2} mostly: broadcast
                float wm = ((M >> bitix) & 1u) ? wgt : 0.0f;
                s0 += ov[q] * wgt;   // sum(outputs*w)
                s1 += wm;            // sum(m*w)
                s2 += ov[q] * wm;    // sum(outputs*w*m)
            }
        }
    }

    // ---- block reduce + device accumulate ----
    #pragma unroll
    for (int off = 32; off > 0; off >>= 1) {
        s0 += __shfl_down(s0, off);
        s1 += __shfl_down(s1, off);
        s2 += __shfl_down(s2, off);
    }
    if (lane == 0) { red[wv][0] = s0; red[wv][1] = s1; red[wv][2] = s2; }
    __syncthreads();
    if (t < 3) {
        float v = red[0][t] + red[1][t] + red[2][t] + red[3][t];
        atomicAdd(&acc[b * 3 + t], v);
        __threadfence();
    }
    __syncthreads();

    // ---- last of 1024 blocks finalizes ----
    if (t == 0) {
        u32 old = __hip_atomic_fetch_add(cnt, 1u, __ATOMIC_ACQ_REL, __HIP_MEMORY_SCOPE_AGENT);
        if (old == 1023u) {
            float s[6];
            #pragma unroll
            for (int k = 0; k < 6; ++k)
                s[k] = __hip_atomic_load(&acc[k], __ATOMIC_ACQUIRE, __HIP_MEMORY_SCOPE_AGENT);
            float loss = 0.0f;
            #pragma unroll
            for (int bb = 0; bb < 2; ++bb) {
                float A = s[bb * 3 + 0], T = s[bb * 3 + 1], I = s[bb * 3 + 2];
                loss += (T == 0.0f) ? 0.0f : (1.0f - 2.0f * I / (A + T + 2e-6f));
            }
            out[0] = 0.5f * loss;
        }
    }
}

extern "C" void kernel_launch(void* const* d_in, const int* in_sizes, int n_in,
                              void* d_out, int out_size, void* d_ws, size_t ws_size,
                              hipStream_t stream) {
    const float* outputs = (const float*)d_in[0];
    const int* masks = (const int*)d_in[1];
    float* out = (float*)d_out;
    float* acc = (float*)d_ws;                       // 6 floats
    u32* cnt = (u32*)((char*)d_ws + 24);             // 1 counter

    hipMemsetAsync(d_ws, 0, 32, stream);
    bbsd_fused<<<1024, 256, 0, stream>>>(outputs, masks, acc, cnt, out);
}

// Round 6
// 129.028 us; speedup vs baseline: 1.8175x; 1.8175x over previous
//
#include <hip/hip_runtime.h>
#include <stdint.h>

typedef unsigned long long u64;
typedef unsigned int u32;

#define HALO 21                  // 20 dilation rounds + 1 for edge stencil => exact interior
#define BAND 64
#define MAXR (BAND + 2 * HALO)   // 106 region rows max

// Block = (slice, row-band). Each block packs its band+halo of the mask
// (coalesced int4 + shuffle-OR), computes edge + <=20 cascaded 3x3 dilations
// entirely in LDS/registers (d0 = first-set round = Chebyshev dist to edge;
// sum_k dilate^k = max(0,21-d0)), then reduces its 64 interior rows of
// outputs with coalesced float4 loads + LDS-broadcast plane lookups.
// 512 blocks -> 2 blocks/CU, 8 waves/CU (R4's 1 wave/SIMD was latency-bound).
// No redundancy blowup (R5's 8x mask re-read thrashed L2: FETCH 85MB).
__global__ __launch_bounds__(256) void bbsd_band(const float* __restrict__ outputs,
                                                 const int* __restrict__ masks,
                                                 float* __restrict__ acc,   // 6 floats, zeroed
                                                 u32* __restrict__ cnt,     // zeroed
                                                 float* __restrict__ out) {
    __shared__ u64 rows[MAXR][5];      // mask bits per region row (+pad col)
    __shared__ u64 tmp[MAXR][5];       // dilation exchange
    __shared__ u64 pw[BAND][4][6];     // interior rows: [row][word][p0..p4, mask]
    __shared__ float wtab[22];
    __shared__ float red[4][3];

    const int t = threadIdx.x;
    const int lane = t & 63, wv = t >> 6;
    const int slice = blockIdx.x >> 2;      // 0..127
    const int band = blockIdx.x & 3;        // 0..3
    const int b = slice >> 6;               // batch
    const int r0 = band * BAND;
    const int rs = (r0 - HALO < 0) ? 0 : r0 - HALO;
    const int re = (r0 + BAND + HALO > 256) ? 256 : r0 + BAND + HALO;
    const int R = re - rs;                  // region rows (85..106)
    const int ioff = r0 - rs;               // interior start within region

    if (t < 22) wtab[t] = 2.0f / (1.0f + __expf(10.0f * (float)(t + 1) * (1.0f / 22.0f)));

    // ---- pack: fully coalesced int4 loads; 16-lane shuffle-OR builds u64 words ----
    {
        const int4* mp = (const int4*)(masks + (size_t)slice * 65536 + (size_t)rs * 256);
        const int total = R * 64;           // int4 units in region (multiple of 64)
        for (int idx = t; idx < total; idx += 256) {
            int4 v = mp[idx];
            u64 w = (u64)(v.x != 0) | ((u64)(v.y != 0) << 1)
                  | ((u64)(v.z != 0) << 2) | ((u64)(v.w != 0) << 3);
            w <<= (t & 15) * 4;
            w |= __shfl_down(w, 8, 16);
            w |= __shfl_down(w, 4, 16);
            w |= __shfl_down(w, 2, 16);
            w |= __shfl_down(w, 1, 16);
            if ((t & 15) == 0) {
                int widx = idx >> 4;                 // u64 word index in region
                rows[widx >> 2][widx & 3] = w;
            }
        }
    }
    __syncthreads();

    // ---- edge + cascaded dilation (owner thread t < R owns region row t) ----
    u64 m[4] = {0, 0, 0, 0}, c[4] = {0, 0, 0, 0};
    u64 p[5][4];
    #pragma unroll
    for (int pl = 0; pl < 5; ++pl)
        #pragma unroll
        for (int j = 0; j < 4; ++j) p[pl][j] = 0ull;

    if (t < R) {
        u64 up[4], dn[4];
        #pragma unroll
        for (int j = 0; j < 4; ++j) {
            m[j] = rows[t][j];
            up[j] = (t > 0)     ? rows[t - 1][j] : 0ull;   // rs==0: true zero-pad; else
            dn[j] = (t < R - 1) ? rows[t + 1][j] : 0ull;   // garbage-at-dist>=21: harmless
        }
        #pragma unroll
        for (int j = 0; j < 4; ++j) {
            u64 lf = (m[j] << 1) | (j > 0 ? (m[j - 1] >> 63) : 0ull);
            u64 rt = (m[j] >> 1) | (j < 3 ? (m[j + 1] << 63) : 0ull);
            c[j] = m[j] & ~(up[j] & dn[j] & lf & rt);      // edge
        }
    }

    for (int k = 1; k <= 20; ++k) {
        if (t < R) {
            #pragma unroll
            for (int j = 0; j < 4; ++j) {
                u64 lf = (c[j] << 1) | (j > 0 ? (c[j - 1] >> 63) : 0ull);
                u64 rt = (c[j] >> 1) | (j < 3 ? (c[j + 1] << 63) : 0ull);
                tmp[t][j] = c[j] | lf | rt;
            }
        }
        __syncthreads();
        int done = 1;
        if (t < R) {
            #pragma unroll
            for (int j = 0; j < 4; ++j) {
                u64 u_ = (t > 0)     ? tmp[t - 1][j] : 0ull;
                u64 d_ = (t < R - 1) ? tmp[t + 1][j] : 0ull;
                u64 n = tmp[t][j] | u_ | d_;
                u64 nw = n & ~c[j];
                c[j] = n;
                #pragma unroll
                for (int pl = 0; pl < 5; ++pl) {
                    u64 sel = (u64)0 - (u64)((k >> pl) & 1);   // branchless, uniform k
                    p[pl][j] |= nw & sel;
                }
            }
            done = ((c[0] & c[1] & c[2] & c[3]) == 0xFFFFFFFFFFFFFFFFull) ? 1 : 0;
        }
        if (__syncthreads_and(done)) break;   // also protects tmp reuse
    }

    // never covered => d0 = 21 (0b10101); then stash interior rows' planes+mask in LDS
    if (t >= ioff && t < ioff + BAND) {
        const int i = t - ioff;
        #pragma unroll
        for (int j = 0; j < 4; ++j) {
            u64 u_ = ~c[j];
            pw[i][j][0] = p[0][j] | u_;
            pw[i][j][1] = p[1][j];
            pw[i][j][2] = p[2][j] | u_;
            pw[i][j][3] = p[3][j];
            pw[i][j][4] = p[4][j] | u_;
            pw[i][j][5] = m[j];
        }
    }
    __syncthreads();

    // ---- reduce: coalesced float4 over the 64 interior rows ----
    float s0 = 0.0f, s1 = 0.0f, s2 = 0.0f;
    {
        const float4* op4 = (const float4*)outputs + (size_t)slice * 16384 + (size_t)r0 * 64;
        #pragma unroll
        for (int it = 0; it < 16; ++it) {
            int idx = it * 256 + t;            // float4 index within band (0..4095)
            float4 o4 = op4[idx];
            int rl = idx >> 6;                 // interior row
            int col = (idx * 4) & 255;
            int w = col >> 6, sh = col & 63;
            u64 P0 = pw[rl][w][0], P1 = pw[rl][w][1], P2 = pw[rl][w][2];
            u64 P3 = pw[rl][w][3], P4 = pw[rl][w][4], M = pw[rl][w][5];
            float ov[4] = {o4.x, o4.y, o4.z, o4.w};
            #pragma unroll
            for (int q = 0; q < 4; ++q) {
                int sq = sh + q;
                int d0 = (int)((P0 >> sq) & 1ull)
                       | ((int)((P1 >> sq) & 1ull) << 1)
                       | ((int)((P2 >> sq) & 1ull) << 2)
                       | ((int)((P3 >> sq) & 1ull) << 3)
                       | ((int)((P4 >> sq) & 1ull) << 4);
                float wgt = wtab[d0];
                float wm = ((M >> sq) & 1ull) ? wgt : 0.0f;
                s0 += ov[q] * wgt;   // sum(outputs*w)
                s1 += wm;            // sum(m*w)
                s2 += ov[q] * wm;    // sum(outputs*w*m)
            }
        }
    }

    // ---- block reduce + device accumulate + last-block finalize ----
    #pragma unroll
    for (int off = 32; off > 0; off >>= 1) {
        s0 += __shfl_down(s0, off);
        s1 += __shfl_down(s1, off);
        s2 += __shfl_down(s2, off);
    }
    if (lane == 0) { red[wv][0] = s0; red[wv][1] = s1; red[wv][2] = s2; }
    __syncthreads();
    if (t < 3) {
        float v = red[0][t] + red[1][t] + red[2][t] + red[3][t];
        atomicAdd(&acc[b * 3 + t], v);
        __threadfence();
    }
    __syncthreads();

    if (t == 0) {
        u32 old = __hip_atomic_fetch_add(cnt, 1u, __ATOMIC_ACQ_REL, __HIP_MEMORY_SCOPE_AGENT);
        if (old == 511u) {
            float s[6];
            #pragma unroll
            for (int k = 0; k < 6; ++k)
                s[k] = __hip_atomic_load(&acc[k], __ATOMIC_ACQUIRE, __HIP_MEMORY_SCOPE_AGENT);
            float loss = 0.0f;
            #pragma unroll
            for (int bb = 0; bb < 2; ++bb) {
                float A = s[bb * 3 + 0], T = s[bb * 3 + 1], I = s[bb * 3 + 2];
                loss += (T == 0.0f) ? 0.0f : (1.0f - 2.0f * I / (A + T + 2e-6f));
            }
            out[0] = 0.5f * loss;
        }
    }
}

extern "C" void kernel_launch(void* const* d_in, const int* in_sizes, int n_in,
                              void* d_out, int out_size, void* d_ws, size_t ws_size,
                              hipStream_t stream) {
    const float* outputs = (const float*)d_in[0];
    const int* masks = (const int*)d_in[1];
    float* out = (float*)d_out;
    float* acc = (float*)d_ws;                 // 6 floats
    u32* cnt = (u32*)((char*)d_ws + 24);       // 1 counter

    hipMemsetAsync(d_ws, 0, 32, stream);
    bbsd_band<<<512, 256, 0, stream>>>(outputs, masks, acc, cnt, out);
}

// Round 7
// 116.450 us; speedup vs baseline: 2.0139x; 1.1080x over previous
//
#include <hip/hip_runtime.h>
#include <stdint.h>

typedef unsigned long long u64;
typedef unsigned int u32;

#define HALO 21                  // 20 dilation rounds + 1 edge stencil => exact interior
#define BAND 64
#define RREG 106                 // uniform region rows per block (BAND + 42)

// Block = (slice, row-band of 64 with 21+ row halo). All global loads are
// batched into register arrays BEFORE any use (R6 was load->use serialized:
// 1-2 loads in flight -> 640 GB/s; batching keeps ~43 loads/wave outstanding).
// d0 = first-covered round of the edge-dilation cascade = Chebyshev distance;
// sum_{k=0..20} dilate^k(edge) = max(0,21-d0); weight = 22-entry LUT.
// No __launch_bounds__ min-waves: the 40-u64 plane array must spill to AGPRs
// (free), not scratch (R5's 134 MB WRITE disaster).
__global__ __launch_bounds__(256) void bbsd_band(const float* __restrict__ outputs,
                                                 const int* __restrict__ masks,
                                                 float* __restrict__ acc,   // 6 floats, zeroed
                                                 u32* __restrict__ cnt,     // zeroed
                                                 float* __restrict__ out) {
    __shared__ u64 rows[RREG][5];      // mask bits per region row (+pad col)
    __shared__ u64 tmp[RREG][5];       // dilation exchange
    __shared__ u64 pw[BAND * 25];      // [row][w*6 + plane(0..4), mask(5)], stride 25
    __shared__ float wtab[22];
    __shared__ float red[4][3];

    const int t = threadIdx.x;
    const int lane = t & 63, wv = t >> 6;
    const int slice = blockIdx.x >> 2;      // 0..127
    const int band = blockIdx.x & 3;        // 0..3
    const int b = slice >> 6;               // batch
    const int r0 = band * BAND;
    const int rs = (band == 0) ? 0 : (band == 3 ? 150 : r0 - HALO - (band == 2 ? 0 : 0));
    // explicit: band0 rs=0, band1 rs=43, band2 rs=107, band3 rs=150
    const int rs2 = (band == 0) ? 0 : (band == 1) ? 43 : (band == 2) ? 107 : 150;
    const int ioff = r0 - rs2;              // interior start within region
    (void)rs;

    if (t < 22) wtab[t] = 2.0f / (1.0f + __expf(10.0f * (float)(t + 1) * (1.0f / 22.0f)));

    // ---- batch-issue ALL global loads (masks first, then outputs) ----
    int4 mv[27];
    {
        const int4* mp = (const int4*)(masks + (size_t)slice * 65536 + (size_t)rs2 * 256);
        #pragma unroll
        for (int i = 0; i < 27; ++i) {
            int idx = i * 256 + t;
            if (idx < RREG * 64) mv[i] = mp[idx];
        }
    }
    float4 o[16];
    {
        const float4* op4 = (const float4*)outputs + (size_t)slice * 16384 + (size_t)r0 * 64;
        #pragma unroll
        for (int i = 0; i < 16; ++i) o[i] = op4[i * 256 + t];
    }

    // ---- pack: nibble + 16-lane shuffle-OR -> u64 words in LDS ----
    #pragma unroll
    for (int i = 0; i < 27; ++i) {
        int idx = i * 256 + t;
        u64 w = 0ull;
        if (idx < RREG * 64) {
            int4 v = mv[i];
            w = (u64)(v.x != 0) | ((u64)(v.y != 0) << 1)
              | ((u64)(v.z != 0) << 2) | ((u64)(v.w != 0) << 3);
        }
        w <<= (t & 15) * 4;
        w |= __shfl_down(w, 8, 16);
        w |= __shfl_down(w, 4, 16);
        w |= __shfl_down(w, 2, 16);
        w |= __shfl_down(w, 1, 16);
        if (((t & 15) == 0) && idx < RREG * 64) {
            int widx = idx >> 4;
            rows[widx >> 2][widx & 3] = w;
        }
    }
    __syncthreads();

    // ---- edge + cascaded dilation (thread t < RREG owns region row t) ----
    u64 m[4] = {0, 0, 0, 0}, c[4] = {0, 0, 0, 0};
    u64 p[5][4];
    #pragma unroll
    for (int pl = 0; pl < 5; ++pl)
        #pragma unroll
        for (int j = 0; j < 4; ++j) p[pl][j] = 0ull;

    if (t < RREG) {
        u64 up[4], dn[4];
        #pragma unroll
        for (int j = 0; j < 4; ++j) {
            m[j] = rows[t][j];
            up[j] = (t > 0)        ? rows[t - 1][j] : 0ull;  // region border: zero-pad; any
            dn[j] = (t < RREG - 1) ? rows[t + 1][j] : 0ull;  // error is >=21 rows from interior
        }
        #pragma unroll
        for (int j = 0; j < 4; ++j) {
            u64 lf = (m[j] << 1) | (j > 0 ? (m[j - 1] >> 63) : 0ull);
            u64 rt = (m[j] >> 1) | (j < 3 ? (m[j + 1] << 63) : 0ull);
            c[j] = m[j] & ~(up[j] & dn[j] & lf & rt);        // edge
        }
    }

    for (int k = 1; k <= 20; ++k) {
        if (t < RREG) {
            #pragma unroll
            for (int j = 0; j < 4; ++j) {
                u64 lf = (c[j] << 1) | (j > 0 ? (c[j - 1] >> 63) : 0ull);
                u64 rt = (c[j] >> 1) | (j < 3 ? (c[j + 1] << 63) : 0ull);
                tmp[t][j] = c[j] | lf | rt;
            }
        }
        __syncthreads();
        int done = 1;
        if (t < RREG) {
            #pragma unroll
            for (int j = 0; j < 4; ++j) {
                u64 u_ = (t > 0)        ? tmp[t - 1][j] : 0ull;
                u64 d_ = (t < RREG - 1) ? tmp[t + 1][j] : 0ull;
                u64 n = tmp[t][j] | u_ | d_;
                u64 nw = n & ~c[j];
                c[j] = n;
                #pragma unroll
                for (int pl = 0; pl < 5; ++pl) {
                    u64 sel = (u64)0 - (u64)((k >> pl) & 1);   // branchless, uniform k
                    p[pl][j] |= nw & sel;
                }
            }
            done = ((c[0] & c[1] & c[2] & c[3]) == 0xFFFFFFFFFFFFFFFFull) ? 1 : 0;
        }
        if (__syncthreads_and(done)) break;   // also protects tmp reuse
    }

    // never covered => d0 = 21 (0b10101); stash interior planes+mask to LDS
    if (t >= ioff && t < ioff + BAND) {
        const int i = t - ioff;
        #pragma unroll
        for (int j = 0; j < 4; ++j) {
            u64 u_ = ~c[j];
            const int base = i * 25 + j * 6;
            pw[base + 0] = p[0][j] | u_;
            pw[base + 1] = p[1][j];
            pw[base + 2] = p[2][j] | u_;
            pw[base + 3] = p[3][j];
            pw[base + 4] = p[4][j] | u_;
            pw[base + 5] = m[j];
        }
    }
    __syncthreads();

    // ---- reduce: outputs already in registers; plane words broadcast from LDS ----
    float s0 = 0.0f, s1 = 0.0f, s2 = 0.0f;
    #pragma unroll
    for (int it = 0; it < 16; ++it) {
        int idx = it * 256 + t;            // float4 index within band
        int rl = idx >> 6;                 // interior row 0..63
        int col = (idx << 2) & 255;
        int w = col >> 6, sh = col & 63;
        const int base = rl * 25 + w * 6;
        u64 P0 = pw[base + 0], P1 = pw[base + 1], P2 = pw[base + 2];
        u64 P3 = pw[base + 3], P4 = pw[base + 4], M = pw[base + 5];
        float ov[4] = {o[it].x, o[it].y, o[it].z, o[it].w};
        #pragma unroll
        for (int q = 0; q < 4; ++q) {
            int sq = sh + q;
            int d0 = (int)((P0 >> sq) & 1ull)
                   | ((int)((P1 >> sq) & 1ull) << 1)
                   | ((int)((P2 >> sq) & 1ull) << 2)
                   | ((int)((P3 >> sq) & 1ull) << 3)
                   | ((int)((P4 >> sq) & 1ull) << 4);
            float wgt = wtab[d0];
            float wm = ((M >> sq) & 1ull) ? wgt : 0.0f;
            s0 += ov[q] * wgt;   // sum(outputs*w)
            s1 += wm;            // sum(m*w)
            s2 += ov[q] * wm;    // sum(outputs*w*m)
        }
    }

    // ---- block reduce + device accumulate + last-block finalize ----
    #pragma unroll
    for (int off = 32; off > 0; off >>= 1) {
        s0 += __shfl_down(s0, off);
        s1 += __shfl_down(s1, off);
        s2 += __shfl_down(s2, off);
    }
    if (lane == 0) { red[wv][0] = s0; red[wv][1] = s1; red[wv][2] = s2; }
    __syncthreads();
    if (t < 3) {
        float v = red[0][t] + red[1][t] + red[2][t] + red[3][t];
        atomicAdd(&acc[b * 3 + t], v);
        __threadfence();
    }
    __syncthreads();

    if (t == 0) {
        u32 old = __hip_atomic_fetch_add(cnt, 1u, __ATOMIC_ACQ_REL, __HIP_MEMORY_SCOPE_AGENT);
        if (old == 511u) {
            float s[6];
            #pragma unroll
            for (int k = 0; k < 6; ++k)
                s[k] = __hip_atomic_load(&acc[k], __ATOMIC_ACQUIRE, __HIP_MEMORY_SCOPE_AGENT);
            float loss = 0.0f;
            #pragma unroll
            for (int bb = 0; bb < 2; ++bb) {
                float A = s[bb * 3 + 0], T = s[bb * 3 + 1], I = s[bb * 3 + 2];
                loss += (T == 0.0f) ? 0.0f : (1.0f - 2.0f * I / (A + T + 2e-6f));
            }
            out[0] = 0.5f * loss;
        }
    }
}

extern "C" void kernel_launch(void* const* d_in, const int* in_sizes, int n_in,
                              void* d_out, int out_size, void* d_ws, size_t ws_size,
                              hipStream_t stream) {
    const float* outputs = (const float*)d_in[0];
    const int* masks = (const int*)d_in[1];
    float* out = (float*)d_out;
    float* acc = (float*)d_ws;                 // 6 floats
    u32* cnt = (u32*)((char*)d_ws + 24);       // 1 counter

    hipMemsetAsync(d_ws, 0, 32, stream);
    bbsd_band<<<512, 256, 0, stream>>>(outputs, masks, acc, cnt, out);
}